// Round 6
// baseline (228.431 us; speedup 1.0000x reference)
//
#include <hip/hip_runtime.h>
#include <hip/hip_bf16.h>

#define B_  4
#define C_  256
#define C2_ 128
#define N_  4096
#define LOG2E 1.4426950408889634f

typedef unsigned short u16;
typedef __attribute__((ext_vector_type(8))) short bf16x8;  // 8 bf16 in 4 VGPRs
typedef __attribute__((ext_vector_type(4))) float f32x4;

static __device__ __forceinline__ u16 f2bf(float f) {
    return __builtin_bit_cast(u16, __float2bfloat16(f));
}
static __device__ __forceinline__ float bf2f(u16 u) {
    return __bfloat162float(__builtin_bit_cast(__hip_bfloat16, u));
}

// ---------------------------------------------------------------------------
// Kernel 0 (prep): fused weight-pack + x-transpose.
//  blocks [0,128):    pack {w_theta,w_phi,w_g,w_out} fp32 -> bf16 into Wb
//                     (4 mats x 32768 elements; Wob = Wb + 3*32768)
//  blocks [128,1152): x [B][C][N] fp32 -> XT [B][N][C] bf16 (LDS transpose)
// ---------------------------------------------------------------------------
__global__ __launch_bounds__(256) void prep_kernel(
    const float* __restrict__ wt, const float* __restrict__ wp,
    const float* __restrict__ wg, const float* __restrict__ wo,
    const float* __restrict__ x, u16* __restrict__ Wb, u16* __restrict__ XT) {
    __shared__ float T[64][65];
    int bid = blockIdx.x;
    int tid = threadIdx.x;
    if (bid < 128) {
        int i = (bid * 256 + tid) * 4;         // [0, 131072)
        int mat = i >> 15, off = i & 32767;
        const float* src = mat == 0 ? wt : (mat == 1 ? wp : (mat == 2 ? wg : wo));
        float4 v = *(const float4*)(src + off);
        ushort4 o = { f2bf(v.x), f2bf(v.y), f2bf(v.z), f2bf(v.w) };
        *(ushort4*)(Wb + i) = o;
        return;
    }
    int bid2 = bid - 128;
    int b   = bid2 / (4 * 64);
    int rem = bid2 % (4 * 64);
    int c0  = (rem / 64) * 64;
    int n0  = (rem % 64) * 64;
#pragma unroll
    for (int it = 0; it < 4; ++it) {
        int idx = it * 256 + tid;
        int rc = idx >> 4, n4 = (idx & 15) * 4;
        float4 v = *(const float4*)(x + ((size_t)b * C_ + c0 + rc) * N_ + n0 + n4);
        T[n4 + 0][rc] = v.x;
        T[n4 + 1][rc] = v.y;
        T[n4 + 2][rc] = v.z;
        T[n4 + 3][rc] = v.w;
    }
    __syncthreads();
#pragma unroll
    for (int it = 0; it < 2; ++it) {
        int idx = it * 256 + tid;
        int nr = idx >> 3, c8 = (idx & 7) * 8;
        u16 o[8];
#pragma unroll
        for (int j = 0; j < 8; ++j) o[j] = f2bf(T[nr][c8 + j]);
        *(uint4*)(XT + ((size_t)b * N_ + n0 + nr) * C_ + c0 + c8) = *(const uint4*)o;
    }
}

// ---------------------------------------------------------------------------
// Kernel 1: MFMA projection. (unchanged from round 5)
// ---------------------------------------------------------------------------
__global__ __launch_bounds__(256) void projm_kernel(
    const u16* __restrict__ XT, const u16* __restrict__ Wb,
    const float* __restrict__ b_theta, const float* __restrict__ b_phi,
    const float* __restrict__ b_g,
    u16* __restrict__ Q, u16* __restrict__ K, u16* __restrict__ V) {
    __shared__ __align__(16) u16 XTs[64][264];  // 33792 B
    __shared__ __align__(16) u16 Vt[128][72];   // 18432 B
    int bid = blockIdx.x;
    int mat = bid / (B_ * (N_ / 64));
    int rem = bid % (B_ * (N_ / 64));
    int b   = rem / (N_ / 64);
    int n0  = (rem % (N_ / 64)) * 64;
    int tid = threadIdx.x;
    int wave = tid >> 6, lane = tid & 63, quad = lane >> 4, l16 = lane & 15;

#pragma unroll
    for (int it = 0; it < 8; ++it) {
        int idx = it * 256 + tid;
        int row = idx >> 5, c8 = (idx & 31) * 8;
        *(uint4*)&XTs[row][c8] =
            *(const uint4*)(XT + ((size_t)b * N_ + n0 + row) * C_ + c8);
    }
    __syncthreads();

    bf16x8 af[8];
#pragma unroll
    for (int ks = 0; ks < 8; ++ks)
        af[ks] = *(const bf16x8*)&XTs[wave * 16 + l16][ks * 32 + quad * 8];

    const u16* wm = Wb + (size_t)mat * C2_ * C_;
    const float* bias = mat == 0 ? b_theta : (mat == 1 ? b_phi : b_g);

    f32x4 acc[8];
#pragma unroll
    for (int i = 0; i < 8; ++i) acc[i] = (f32x4){0.f, 0.f, 0.f, 0.f};
#pragma unroll
    for (int ct = 0; ct < 8; ++ct) {
        const u16* wr = wm + (size_t)(ct * 16 + l16) * C_ + quad * 8;
#pragma unroll
        for (int ks = 0; ks < 8; ++ks) {
            bf16x8 bf = *(const bf16x8*)(wr + ks * 32);
            acc[ct] = __builtin_amdgcn_mfma_f32_16x16x32_bf16(af[ks], bf, acc[ct], 0, 0, 0);
        }
    }

    if (mat < 2) {
        u16* dst = mat == 0 ? Q : K;
        float sc = mat == 0 ? LOG2E : 1.0f;
#pragma unroll
        for (int ct = 0; ct < 8; ++ct) {
            float bb = bias[ct * 16 + l16];
#pragma unroll
            for (int r = 0; r < 4; ++r) {
                int n = n0 + wave * 16 + quad * 4 + r;
                dst[((size_t)b * N_ + n) * C2_ + ct * 16 + l16] =
                    f2bf((acc[ct][r] + bb) * sc);
            }
        }
    } else {
#pragma unroll
        for (int ct = 0; ct < 8; ++ct) {
            float bb = bias[ct * 16 + l16];
#pragma unroll
            for (int r = 0; r < 4; ++r)
                Vt[ct * 16 + l16][wave * 16 + quad * 4 + r] = f2bf(acc[ct][r] + bb);
        }
        __syncthreads();
#pragma unroll
        for (int it = 0; it < 4; ++it) {
            int idx = it * 256 + tid;
            int row = idx >> 3, n8 = (idx & 7) * 8;
            *(uint4*)(V + ((size_t)b * C2_ + row) * N_ + n0 + n8) =
                *(const uint4*)&Vt[row][n8];
        }
    }
}

// ---------------------------------------------------------------------------
// Kernel 2: flash attention = round-5 structure (BM=128, 4 waves x 32 rows,
// separate correctly-sized Ps, 2 barriers/iter) + register prefetch of the
// next K/V tile (r3's overflow bug was Ps-in-Ks sizing, not the prefetch).
// LDS = 54272 B. grid = B*(N/128)*nsplit, 256 thr.
// ---------------------------------------------------------------------------
__global__ __launch_bounds__(256, 2) void attn_kernel(
    const u16* __restrict__ Q, const u16* __restrict__ K,
    const u16* __restrict__ V, u16* __restrict__ AO,
    float* __restrict__ Op, float* __restrict__ lsum, int nsplit) {
    const int BM = 128, BN = 64, D = C2_;
    const int per = B_ * (N_ / BM);      // 128
    int s    = blockIdx.x / per;
    int r0   = blockIdx.x % per;
    int b    = r0 / (N_ / BM);
    int m0   = (r0 % (N_ / BM)) * BM;
    int tid  = threadIdx.x;
    int wave = tid >> 6, lane = tid & 63, quad = (lane >> 4) & 3, l16 = lane & 15;

    __shared__ __align__(16) u16 Ks[BN][D + 8];        // 17408 B
    __shared__ __align__(16) u16 Vs[D][BN + 8];        // 18432 B
    __shared__ __align__(16) u16 Psb[4][32][BN + 8];   // 18432 B
    u16* Ps = &Psb[wave][0][0];

    // Q fragments for 2 m-subtiles: A[m=l16][k=kk*32+quad*8+j]
    bf16x8 qf[2][4];
#pragma unroll
    for (int ms = 0; ms < 2; ++ms) {
        const u16* qp = Q + ((size_t)b * N_ + m0 + wave * 32 + ms * 16 + l16) * D;
#pragma unroll
        for (int kk = 0; kk < 4; ++kk)
            qf[ms][kk] = *(const bf16x8*)(qp + kk * 32 + quad * 8);
    }

    float l_r[2][4] = {{0.f, 0.f, 0.f, 0.f}, {0.f, 0.f, 0.f, 0.f}};
    f32x4 o_acc[2][8];
#pragma unroll
    for (int ms = 0; ms < 2; ++ms)
#pragma unroll
        for (int i = 0; i < 8; ++i) o_acc[ms][i] = (f32x4){0.f, 0.f, 0.f, 0.f};

    const int chunk = N_ / nsplit;
    const int nt0 = s * chunk, nt1 = nt0 + chunk;

    // prefetch registers: 4 x 16B (K) + 4 x 16B (V) per thread
    uint4 kr[4], vr[4];
    const u16* Kb = K + (size_t)b * N_ * D;
    const u16* Vb = V + (size_t)b * C2_ * N_;
    {
        const u16* kp = Kb + (size_t)nt0 * D;
        const u16* vp = Vb + nt0;
#pragma unroll
        for (int it = 0; it < 4; ++it) {
            int idx = it * 256 + tid;
            kr[it] = *(const uint4*)(kp + (idx >> 4) * D + (idx & 15) * 8);
            vr[it] = *(const uint4*)(vp + (size_t)(idx >> 3) * N_ + (idx & 7) * 8);
        }
    }

    for (int nt = nt0; nt < nt1; nt += BN) {
        // ---- commit prefetched tile to LDS ----
#pragma unroll
        for (int it = 0; it < 4; ++it) {
            int idx = it * 256 + tid;
            *(uint4*)&Ks[idx >> 4][(idx & 15) * 8] = kr[it];
            *(uint4*)&Vs[idx >> 3][(idx & 7) * 8]  = vr[it];
        }
        __syncthreads();

        // ---- issue next tile's global loads (in flight during compute) ----
        int ntn = nt + BN;
        if (ntn < nt1) {
            const u16* kp = Kb + (size_t)ntn * D;
            const u16* vp = Vb + ntn;
#pragma unroll
            for (int it = 0; it < 4; ++it) {
                int idx = it * 256 + tid;
                kr[it] = *(const uint4*)(kp + (idx >> 4) * D + (idx & 15) * 8);
                vr[it] = *(const uint4*)(vp + (size_t)(idx >> 3) * N_ + (idx & 7) * 8);
            }
        }

        // ---- S = Q K^T : each kf read feeds both m-subtiles ----
        f32x4 sc[2][4];
#pragma unroll
        for (int nn = 0; nn < 4; ++nn) {
            f32x4 a0 = (f32x4){0.f, 0.f, 0.f, 0.f};
            f32x4 a1 = (f32x4){0.f, 0.f, 0.f, 0.f};
#pragma unroll
            for (int kk = 0; kk < 4; ++kk) {
                bf16x8 kf = *(const bf16x8*)&Ks[nn * 16 + l16][kk * 32 + quad * 8];
                a0 = __builtin_amdgcn_mfma_f32_16x16x32_bf16(qf[0][kk], kf, a0, 0, 0, 0);
                a1 = __builtin_amdgcn_mfma_f32_16x16x32_bf16(qf[1][kk], kf, a1, 0, 0, 0);
            }
            sc[0][nn] = a0;
            sc[1][nn] = a1;
        }

        // ---- p = 2^s; per-lane partial row sums; P -> own Ps region ----
#pragma unroll
        for (int ms = 0; ms < 2; ++ms)
#pragma unroll
            for (int nn = 0; nn < 4; ++nn)
#pragma unroll
                for (int r = 0; r < 4; ++r) {
                    float p = __builtin_amdgcn_exp2f(sc[ms][nn][r]);
                    l_r[ms][r] += p;
                    Ps[(ms * 16 + quad * 4 + r) * (BN + 8) + nn * 16 + l16] = f2bf(p);
                }

        // ---- O += P V : each vf read feeds both m-subtiles ----
#pragma unroll
        for (int ks = 0; ks < 2; ++ks) {
            bf16x8 pf0 = *(const bf16x8*)&Ps[(l16) * (BN + 8) + ks * 32 + quad * 8];
            bf16x8 pf1 = *(const bf16x8*)&Ps[(16 + l16) * (BN + 8) + ks * 32 + quad * 8];
#pragma unroll
            for (int cs = 0; cs < 8; ++cs) {
                bf16x8 vf = *(const bf16x8*)&Vs[cs * 16 + l16][ks * 32 + quad * 8];
                o_acc[0][cs] = __builtin_amdgcn_mfma_f32_16x16x32_bf16(pf0, vf, o_acc[0][cs], 0, 0, 0);
                o_acc[1][cs] = __builtin_amdgcn_mfma_f32_16x16x32_bf16(pf1, vf, o_acc[1][cs], 0, 0, 0);
            }
        }
        __syncthreads();   // Ks/Vs free for next commit
    }

    // one shuffle-reduce of row sums at the end
#pragma unroll
    for (int ms = 0; ms < 2; ++ms)
#pragma unroll
        for (int r = 0; r < 4; ++r) {
            l_r[ms][r] += __shfl_xor(l_r[ms][r], 1);
            l_r[ms][r] += __shfl_xor(l_r[ms][r], 2);
            l_r[ms][r] += __shfl_xor(l_r[ms][r], 4);
            l_r[ms][r] += __shfl_xor(l_r[ms][r], 8);
        }

    if (Op) {
#pragma unroll
        for (int ms = 0; ms < 2; ++ms) {
#pragma unroll
            for (int cs = 0; cs < 8; ++cs)
#pragma unroll
                for (int r = 0; r < 4; ++r) {
                    size_t row = (size_t)s * (B_ * N_) + (size_t)b * N_ +
                                 m0 + wave * 32 + ms * 16 + quad * 4 + r;
                    Op[row * C2_ + cs * 16 + l16] = o_acc[ms][cs][r];
                }
            if (l16 == 0)
#pragma unroll
                for (int r = 0; r < 4; ++r) {
                    size_t row = (size_t)s * (B_ * N_) + (size_t)b * N_ +
                                 m0 + wave * 32 + ms * 16 + quad * 4 + r;
                    lsum[row] = l_r[ms][r];
                }
        }
    } else {
#pragma unroll
        for (int ms = 0; ms < 2; ++ms)
#pragma unroll
            for (int cs = 0; cs < 8; ++cs)
#pragma unroll
                for (int r = 0; r < 4; ++r) {
                    float v = o_acc[ms][cs][r] / l_r[ms][r];
                    AO[((size_t)b * N_ + m0 + wave * 32 + ms * 16 + quad * 4 + r) * C2_ +
                       cs * 16 + l16] = f2bf(v);
                }
    }
}

// ---------------------------------------------------------------------------
// Kernel 2b: combine split-K partials (fixed max => plain sums). (unchanged)
// ---------------------------------------------------------------------------
__global__ __launch_bounds__(256) void combine_kernel(
    const float* __restrict__ Op, const float* __restrict__ lsum,
    u16* __restrict__ AO, int nsplit) {
    int tid = threadIdx.x;
    int row_in = tid >> 5;
    int cq = (tid & 31) * 4;
    size_t row = (size_t)blockIdx.x * 8 + row_in;

    float L = 0.f;
    float4 acc = {0.f, 0.f, 0.f, 0.f};
    for (int s = 0; s < nsplit; ++s) {
        L += lsum[(size_t)s * (B_ * N_) + row];
        float4 v = *(const float4*)(Op + ((size_t)s * (B_ * N_) + row) * C2_ + cq);
        acc.x += v.x; acc.y += v.y; acc.z += v.z; acc.w += v.w;
    }
    float inv = 1.f / L;
    ushort4 o = { f2bf(acc.x * inv), f2bf(acc.y * inv),
                  f2bf(acc.z * inv), f2bf(acc.w * inv) };
    *(ushort4*)&AO[row * C2_ + cq] = o;
}

// ---------------------------------------------------------------------------
// Kernel 3: outproj via MFMA, zero LDS / zero barriers.
// y[c][n] = x[c][n] + b_out[c] + sum_c2 w_out[c][c2] * AO[n][c2]
// A-frag = Wob rows (bf16, packed in prep); B-frag = AO rows (16B contig).
// Block = 4 waves = 64 c-rows x 64 n. grid = B*(C/64)*(N/64) = 1024.
// ---------------------------------------------------------------------------
__global__ __launch_bounds__(256) void outproj_kernel(
    const float* __restrict__ x, const u16* __restrict__ AO,
    const u16* __restrict__ Wob, const float* __restrict__ b_out,
    float* __restrict__ y) {
    int bid = blockIdx.x;
    int per_b = (C_ / 64) * (N_ / 64);   // 256
    int b   = bid / per_b;
    int rem = bid % per_b;
    int c0  = (rem / (N_ / 64)) * 64;
    int n0  = (rem % (N_ / 64)) * 64;
    int tid = threadIdx.x;
    int wave = tid >> 6, lane = tid & 63, quad = lane >> 4, l16 = lane & 15;
    int cw = c0 + wave * 16;

    // A-frags: w_out rows [c=cw+l16][k=c2]
    bf16x8 af[4];
#pragma unroll
    for (int kk = 0; kk < 4; ++kk)
        af[kk] = *(const bf16x8*)&Wob[(size_t)(cw + l16) * C2_ + kk * 32 + quad * 8];

    f32x4 acc[4];
#pragma unroll
    for (int i = 0; i < 4; ++i) acc[i] = (f32x4){0.f, 0.f, 0.f, 0.f};

#pragma unroll
    for (int nn = 0; nn < 4; ++nn) {
        const u16* ap = AO + ((size_t)b * N_ + n0 + nn * 16 + l16) * C2_ + quad * 8;
#pragma unroll
        for (int kk = 0; kk < 4; ++kk) {
            bf16x8 bf = *(const bf16x8*)(ap + kk * 32);
            acc[nn] = __builtin_amdgcn_mfma_f32_16x16x32_bf16(af[kk], bf, acc[nn], 0, 0, 0);
        }
    }

    float bo[4];
#pragma unroll
    for (int r = 0; r < 4; ++r) bo[r] = b_out[cw + quad * 4 + r];

#pragma unroll
    for (int nn = 0; nn < 4; ++nn)
#pragma unroll
        for (int r = 0; r < 4; ++r) {
            int c = cw + quad * 4 + r;
            size_t off = ((size_t)b * C_ + c) * N_ + n0 + nn * 16 + l16;
            y[off] = x[off] + bo[r] + acc[nn][r];
        }
}

// ---------------------------------------------------------------------------
extern "C" void kernel_launch(void* const* d_in, const int* in_sizes, int n_in,
                              void* d_out, int out_size, void* d_ws, size_t ws_size,
                              hipStream_t stream) {
    const float* x       = (const float*)d_in[0];
    const float* w_theta = (const float*)d_in[1];
    const float* b_theta = (const float*)d_in[2];
    const float* w_phi   = (const float*)d_in[3];
    const float* b_phi   = (const float*)d_in[4];
    const float* w_g     = (const float*)d_in[5];
    const float* b_g     = (const float*)d_in[6];
    const float* w_out   = (const float*)d_in[7];
    const float* b_out   = (const float*)d_in[8];
    float* y = (float*)d_out;

    const size_t SZ = (size_t)B_ * N_ * C2_;        // 2Mi elements
    u16* Q  = (u16*)d_ws;
    u16* K  = Q + SZ;
    u16* V  = K + SZ;
    u16* AO = V + SZ;
    u16* Wb = AO + SZ;                               // 4 mats x 32768 = 256 KiB
    u16* Wob = Wb + (size_t)3 * C2_ * C_;
    u16* XT = Wb + (size_t)4 * C2_ * C_;             // 8 MiB
    char* dyn = (char*)(XT + (size_t)B_ * N_ * C_);
    size_t fixedB = (size_t)(dyn - (char*)d_ws);     // ~24.5 MiB

    size_t perS = SZ * 4 + (size_t)B_ * N_ * 4;      // Op + lsum per split

    int S;
    if      (ws_size >= fixedB + 4 * perS) S = 4;
    else if (ws_size >= fixedB + 2 * perS) S = 2;
    else                                   S = 1;

    float* Op = nullptr;
    float* ls = nullptr;
    if (S > 1) {
        Op = (float*)dyn;
        ls = Op + (size_t)S * SZ;
    }

    prep_kernel<<<128 + B_ * (C_ / 64) * (N_ / 64), 256, 0, stream>>>(
        w_theta, w_phi, w_g, w_out, x, Wb, XT);
    projm_kernel<<<3 * B_ * (N_ / 64), 256, 0, stream>>>(
        XT, Wb, b_theta, b_phi, b_g, Q, K, V);
    attn_kernel<<<B_ * (N_ / 128) * S, 256, 0, stream>>>(Q, K, V, AO, Op, ls, S);
    if (S > 1)
        combine_kernel<<<B_ * N_ / 8, 256, 0, stream>>>(Op, ls, AO, S);
    outproj_kernel<<<B_ * (C_ / 64) * (N_ / 64), 256, 0, stream>>>(
        x, AO, Wob, b_out, y);
}

// Round 7
// 179.195 us; speedup vs baseline: 1.2748x; 1.2748x over previous
//
#include <hip/hip_runtime.h>
#include <hip/hip_bf16.h>

#define B_  4
#define C_  256
#define C2_ 128
#define N_  4096
#define LOG2E 1.4426950408889634f

typedef unsigned short u16;
typedef __attribute__((ext_vector_type(8))) short bf16x8;  // 8 bf16 in 4 VGPRs
typedef __attribute__((ext_vector_type(4))) float f32x4;

static __device__ __forceinline__ u16 f2bf(float f) {
    return __builtin_bit_cast(u16, __float2bfloat16(f));
}
static __device__ __forceinline__ float bf2f(u16 u) {
    return __bfloat162float(__builtin_bit_cast(__hip_bfloat16, u));
}

// ---------------------------------------------------------------------------
// Kernel 0 (prep): fused weight-pack + x-transpose. (unchanged from round 6)
//  blocks [0,128):    pack {w_theta,w_phi,w_g,w_out} fp32 -> bf16 into Wb
//  blocks [128,1152): x [B][C][N] fp32 -> XT [B][N][C] bf16 (LDS transpose)
// ---------------------------------------------------------------------------
__global__ __launch_bounds__(256) void prep_kernel(
    const float* __restrict__ wt, const float* __restrict__ wp,
    const float* __restrict__ wg, const float* __restrict__ wo,
    const float* __restrict__ x, u16* __restrict__ Wb, u16* __restrict__ XT) {
    __shared__ float T[64][65];
    int bid = blockIdx.x;
    int tid = threadIdx.x;
    if (bid < 128) {
        int i = (bid * 256 + tid) * 4;         // [0, 131072)
        int mat = i >> 15, off = i & 32767;
        const float* src = mat == 0 ? wt : (mat == 1 ? wp : (mat == 2 ? wg : wo));
        float4 v = *(const float4*)(src + off);
        ushort4 o = { f2bf(v.x), f2bf(v.y), f2bf(v.z), f2bf(v.w) };
        *(ushort4*)(Wb + i) = o;
        return;
    }
    int bid2 = bid - 128;
    int b   = bid2 / (4 * 64);
    int rem = bid2 % (4 * 64);
    int c0  = (rem / 64) * 64;
    int n0  = (rem % 64) * 64;
#pragma unroll
    for (int it = 0; it < 4; ++it) {
        int idx = it * 256 + tid;
        int rc = idx >> 4, n4 = (idx & 15) * 4;
        float4 v = *(const float4*)(x + ((size_t)b * C_ + c0 + rc) * N_ + n0 + n4);
        T[n4 + 0][rc] = v.x;
        T[n4 + 1][rc] = v.y;
        T[n4 + 2][rc] = v.z;
        T[n4 + 3][rc] = v.w;
    }
    __syncthreads();
#pragma unroll
    for (int it = 0; it < 2; ++it) {
        int idx = it * 256 + tid;
        int nr = idx >> 3, c8 = (idx & 7) * 8;
        u16 o[8];
#pragma unroll
        for (int j = 0; j < 8; ++j) o[j] = f2bf(T[nr][c8 + j]);
        *(uint4*)(XT + ((size_t)b * N_ + n0 + nr) * C_ + c0 + c8) = *(const uint4*)o;
    }
}

// ---------------------------------------------------------------------------
// Kernel 1: MFMA projection. (unchanged)
// ---------------------------------------------------------------------------
__global__ __launch_bounds__(256) void projm_kernel(
    const u16* __restrict__ XT, const u16* __restrict__ Wb,
    const float* __restrict__ b_theta, const float* __restrict__ b_phi,
    const float* __restrict__ b_g,
    u16* __restrict__ Q, u16* __restrict__ K, u16* __restrict__ V) {
    __shared__ __align__(16) u16 XTs[64][264];  // 33792 B
    __shared__ __align__(16) u16 Vt[128][72];   // 18432 B
    int bid = blockIdx.x;
    int mat = bid / (B_ * (N_ / 64));
    int rem = bid % (B_ * (N_ / 64));
    int b   = rem / (N_ / 64);
    int n0  = (rem % (N_ / 64)) * 64;
    int tid = threadIdx.x;
    int wave = tid >> 6, lane = tid & 63, quad = lane >> 4, l16 = lane & 15;

#pragma unroll
    for (int it = 0; it < 8; ++it) {
        int idx = it * 256 + tid;
        int row = idx >> 5, c8 = (idx & 31) * 8;
        *(uint4*)&XTs[row][c8] =
            *(const uint4*)(XT + ((size_t)b * N_ + n0 + row) * C_ + c8);
    }
    __syncthreads();

    bf16x8 af[8];
#pragma unroll
    for (int ks = 0; ks < 8; ++ks)
        af[ks] = *(const bf16x8*)&XTs[wave * 16 + l16][ks * 32 + quad * 8];

    const u16* wm = Wb + (size_t)mat * C2_ * C_;
    const float* bias = mat == 0 ? b_theta : (mat == 1 ? b_phi : b_g);

    f32x4 acc[8];
#pragma unroll
    for (int i = 0; i < 8; ++i) acc[i] = (f32x4){0.f, 0.f, 0.f, 0.f};
#pragma unroll
    for (int ct = 0; ct < 8; ++ct) {
        const u16* wr = wm + (size_t)(ct * 16 + l16) * C_ + quad * 8;
#pragma unroll
        for (int ks = 0; ks < 8; ++ks) {
            bf16x8 bf = *(const bf16x8*)(wr + ks * 32);
            acc[ct] = __builtin_amdgcn_mfma_f32_16x16x32_bf16(af[ks], bf, acc[ct], 0, 0, 0);
        }
    }

    if (mat < 2) {
        u16* dst = mat == 0 ? Q : K;
        float sc = mat == 0 ? LOG2E : 1.0f;
#pragma unroll
        for (int ct = 0; ct < 8; ++ct) {
            float bb = bias[ct * 16 + l16];
#pragma unroll
            for (int r = 0; r < 4; ++r) {
                int n = n0 + wave * 16 + quad * 4 + r;
                dst[((size_t)b * N_ + n) * C2_ + ct * 16 + l16] =
                    f2bf((acc[ct][r] + bb) * sc);
            }
        }
    } else {
#pragma unroll
        for (int ct = 0; ct < 8; ++ct) {
            float bb = bias[ct * 16 + l16];
#pragma unroll
            for (int r = 0; r < 4; ++r)
                Vt[ct * 16 + l16][wave * 16 + quad * 4 + r] = f2bf(acc[ct][r] + bb);
        }
        __syncthreads();
#pragma unroll
        for (int it = 0; it < 4; ++it) {
            int idx = it * 256 + tid;
            int row = idx >> 3, n8 = (idx & 7) * 8;
            *(uint4*)(V + ((size_t)b * C2_ + row) * N_ + n0 + n8) =
                *(const uint4*)&Vt[row][n8];
        }
    }
}

// ---------------------------------------------------------------------------
// Kernel 2: flash attention — EXACT round-5 kernel (56.4 µs proven).
// BM=128: 4 waves x 32 m-rows, separate correctly-sized Ps, 2 barriers/iter,
// synchronous staging (register prefetch REVERTED: it spilled to scratch,
// +200 MB of writes — r6 post-mortem).
// ---------------------------------------------------------------------------
__global__ __launch_bounds__(256, 2) void attn_kernel(
    const u16* __restrict__ Q, const u16* __restrict__ K,
    const u16* __restrict__ V, u16* __restrict__ AO,
    float* __restrict__ Op, float* __restrict__ lsum, int nsplit) {
    const int BM = 128, BN = 64, D = C2_;
    const int per = B_ * (N_ / BM);      // 128
    int s    = blockIdx.x / per;
    int r0   = blockIdx.x % per;
    int b    = r0 / (N_ / BM);
    int m0   = (r0 % (N_ / BM)) * BM;
    int tid  = threadIdx.x;
    int wave = tid >> 6, lane = tid & 63, quad = (lane >> 4) & 3, l16 = lane & 15;

    __shared__ __align__(16) u16 Ks[BN][D + 8];        // 17408 B
    __shared__ __align__(16) u16 Vs[D][BN + 8];        // 18432 B
    __shared__ __align__(16) u16 Psb[4][32][BN + 8];   // 18432 B
    u16* Ps = &Psb[wave][0][0];

    bf16x8 qf[2][4];
#pragma unroll
    for (int ms = 0; ms < 2; ++ms) {
        const u16* qp = Q + ((size_t)b * N_ + m0 + wave * 32 + ms * 16 + l16) * D;
#pragma unroll
        for (int kk = 0; kk < 4; ++kk)
            qf[ms][kk] = *(const bf16x8*)(qp + kk * 32 + quad * 8);
    }

    float l_r[2][4] = {{0.f, 0.f, 0.f, 0.f}, {0.f, 0.f, 0.f, 0.f}};
    f32x4 o_acc[2][8];
#pragma unroll
    for (int ms = 0; ms < 2; ++ms)
#pragma unroll
        for (int i = 0; i < 8; ++i) o_acc[ms][i] = (f32x4){0.f, 0.f, 0.f, 0.f};

    const int chunk = N_ / nsplit;
    const int nt0 = s * chunk, nt1 = nt0 + chunk;

    for (int nt = nt0; nt < nt1; nt += BN) {
        const u16* kp = K + ((size_t)b * N_ + nt) * D;
#pragma unroll
        for (int it = 0; it < 4; ++it) {
            int idx = it * 256 + tid;
            int row = idx >> 4, col = (idx & 15) * 8;
            *(uint4*)&Ks[row][col] = *(const uint4*)(kp + row * D + col);
        }
#pragma unroll
        for (int it = 0; it < 4; ++it) {
            int idx = it * 256 + tid;
            int row = idx >> 3, col = (idx & 7) * 8;
            *(uint4*)&Vs[row][col] =
                *(const uint4*)(V + ((size_t)b * C2_ + row) * N_ + nt + col);
        }
        __syncthreads();

        f32x4 sc[2][4];
#pragma unroll
        for (int nn = 0; nn < 4; ++nn) {
            f32x4 a0 = (f32x4){0.f, 0.f, 0.f, 0.f};
            f32x4 a1 = (f32x4){0.f, 0.f, 0.f, 0.f};
#pragma unroll
            for (int kk = 0; kk < 4; ++kk) {
                bf16x8 kf = *(const bf16x8*)&Ks[nn * 16 + l16][kk * 32 + quad * 8];
                a0 = __builtin_amdgcn_mfma_f32_16x16x32_bf16(qf[0][kk], kf, a0, 0, 0, 0);
                a1 = __builtin_amdgcn_mfma_f32_16x16x32_bf16(qf[1][kk], kf, a1, 0, 0, 0);
            }
            sc[0][nn] = a0;
            sc[1][nn] = a1;
        }

#pragma unroll
        for (int ms = 0; ms < 2; ++ms)
#pragma unroll
            for (int nn = 0; nn < 4; ++nn)
#pragma unroll
                for (int r = 0; r < 4; ++r) {
                    float p = __builtin_amdgcn_exp2f(sc[ms][nn][r]);
                    l_r[ms][r] += p;
                    Ps[(ms * 16 + quad * 4 + r) * (BN + 8) + nn * 16 + l16] = f2bf(p);
                }

#pragma unroll
        for (int ks = 0; ks < 2; ++ks) {
            bf16x8 pf0 = *(const bf16x8*)&Ps[(l16) * (BN + 8) + ks * 32 + quad * 8];
            bf16x8 pf1 = *(const bf16x8*)&Ps[(16 + l16) * (BN + 8) + ks * 32 + quad * 8];
#pragma unroll
            for (int cs = 0; cs < 8; ++cs) {
                bf16x8 vf = *(const bf16x8*)&Vs[cs * 16 + l16][ks * 32 + quad * 8];
                o_acc[0][cs] = __builtin_amdgcn_mfma_f32_16x16x32_bf16(pf0, vf, o_acc[0][cs], 0, 0, 0);
                o_acc[1][cs] = __builtin_amdgcn_mfma_f32_16x16x32_bf16(pf1, vf, o_acc[1][cs], 0, 0, 0);
            }
        }
        __syncthreads();
    }

#pragma unroll
    for (int ms = 0; ms < 2; ++ms)
#pragma unroll
        for (int r = 0; r < 4; ++r) {
            l_r[ms][r] += __shfl_xor(l_r[ms][r], 1);
            l_r[ms][r] += __shfl_xor(l_r[ms][r], 2);
            l_r[ms][r] += __shfl_xor(l_r[ms][r], 4);
            l_r[ms][r] += __shfl_xor(l_r[ms][r], 8);
        }

    if (Op) {
#pragma unroll
        for (int ms = 0; ms < 2; ++ms) {
#pragma unroll
            for (int cs = 0; cs < 8; ++cs)
#pragma unroll
                for (int r = 0; r < 4; ++r) {
                    size_t row = (size_t)s * (B_ * N_) + (size_t)b * N_ +
                                 m0 + wave * 32 + ms * 16 + quad * 4 + r;
                    Op[row * C2_ + cs * 16 + l16] = o_acc[ms][cs][r];
                }
            if (l16 == 0)
#pragma unroll
                for (int r = 0; r < 4; ++r) {
                    size_t row = (size_t)s * (B_ * N_) + (size_t)b * N_ +
                                 m0 + wave * 32 + ms * 16 + quad * 4 + r;
                    lsum[row] = l_r[ms][r];
                }
        }
    } else {
#pragma unroll
        for (int ms = 0; ms < 2; ++ms)
#pragma unroll
            for (int cs = 0; cs < 8; ++cs)
#pragma unroll
                for (int r = 0; r < 4; ++r) {
                    float v = o_acc[ms][cs][r] / l_r[ms][r];
                    AO[((size_t)b * N_ + m0 + wave * 32 + ms * 16 + quad * 4 + r) * C2_ +
                       cs * 16 + l16] = f2bf(v);
                }
    }
}

// ---------------------------------------------------------------------------
// Kernel 3: outproj with FUSED split-K combine.
//  stage: combined+normalized AO tile [64 n][128 c2] bf16 -> LDS
//         (from Op fp32 partials + lsum if nsplit>1, else from AO)
//  mfma:  y[c][n] = x[c][n] + b_out[c] + w_out[c,:] . AO[n,:]
// Block = 4 waves = 64 c x 64 n. grid = B*(C/64)*(N/64) = 1024.
// ---------------------------------------------------------------------------
__global__ __launch_bounds__(256) void outproj_kernel(
    const float* __restrict__ x, const float* __restrict__ Op,
    const float* __restrict__ lsum, const u16* __restrict__ AO,
    const u16* __restrict__ Wob, const float* __restrict__ b_out,
    float* __restrict__ y, int nsplit) {
    __shared__ __align__(16) u16 As[64][C2_ + 8];   // 17408 B
    __shared__ float Ls[64];
    int bid = blockIdx.x;
    int per_b = (C_ / 64) * (N_ / 64);   // 256
    int b   = bid / per_b;
    int rem = bid % per_b;
    int c0  = (rem / (N_ / 64)) * 64;
    int n0  = (rem % (N_ / 64)) * 64;
    int tid = threadIdx.x;
    int wave = tid >> 6, lane = tid & 63, quad = lane >> 4, l16 = lane & 15;

    if (nsplit > 1) {   // grid-uniform branch
        if (tid < 64) {
            float L = 0.f;
            for (int s = 0; s < nsplit; ++s)
                L += lsum[(size_t)s * (B_ * N_) + (size_t)b * N_ + n0 + tid];
            Ls[tid] = 1.f / L;
        }
        __syncthreads();
#pragma unroll
        for (int it = 0; it < 8; ++it) {
            int idx = it * 256 + tid;           // 64 rows x 32 float4
            int n = idx >> 5, c4 = (idx & 31) * 4;
            float4 a = {0.f, 0.f, 0.f, 0.f};
            for (int s = 0; s < nsplit; ++s) {
                float4 v = *(const float4*)(
                    Op + ((size_t)s * (B_ * N_) + (size_t)b * N_ + n0 + n) * C2_ + c4);
                a.x += v.x; a.y += v.y; a.z += v.z; a.w += v.w;
            }
            float inv = Ls[n];
            ushort4 o = { f2bf(a.x * inv), f2bf(a.y * inv),
                          f2bf(a.z * inv), f2bf(a.w * inv) };
            *(ushort4*)&As[n][c4] = o;
        }
    } else {
#pragma unroll
        for (int it = 0; it < 4; ++it) {
            int idx = it * 256 + tid;           // 64 rows x 16 uint4
            int n = idx >> 4, c8 = (idx & 15) * 8;
            *(uint4*)&As[n][c8] =
                *(const uint4*)(AO + ((size_t)b * N_ + n0 + n) * C2_ + c8);
        }
    }
    __syncthreads();

    int cw = c0 + wave * 16;
    // A-frags: w_out rows [c=cw+l16][k=c2]
    bf16x8 af[4];
#pragma unroll
    for (int kk = 0; kk < 4; ++kk)
        af[kk] = *(const bf16x8*)&Wob[(size_t)(cw + l16) * C2_ + kk * 32 + quad * 8];

    f32x4 acc[4];
#pragma unroll
    for (int i = 0; i < 4; ++i) acc[i] = (f32x4){0.f, 0.f, 0.f, 0.f};

#pragma unroll
    for (int nn = 0; nn < 4; ++nn)
#pragma unroll
        for (int kk = 0; kk < 4; ++kk) {
            bf16x8 bf = *(const bf16x8*)&As[nn * 16 + l16][kk * 32 + quad * 8];
            acc[nn] = __builtin_amdgcn_mfma_f32_16x16x32_bf16(af[kk], bf, acc[nn], 0, 0, 0);
        }

    float bo[4];
#pragma unroll
    for (int r = 0; r < 4; ++r) bo[r] = b_out[cw + quad * 4 + r];

#pragma unroll
    for (int nn = 0; nn < 4; ++nn)
#pragma unroll
        for (int r = 0; r < 4; ++r) {
            int c = cw + quad * 4 + r;
            size_t off = ((size_t)b * C_ + c) * N_ + n0 + nn * 16 + l16;
            y[off] = x[off] + bo[r] + acc[nn][r];
        }
}

// ---------------------------------------------------------------------------
extern "C" void kernel_launch(void* const* d_in, const int* in_sizes, int n_in,
                              void* d_out, int out_size, void* d_ws, size_t ws_size,
                              hipStream_t stream) {
    const float* x       = (const float*)d_in[0];
    const float* w_theta = (const float*)d_in[1];
    const float* b_theta = (const float*)d_in[2];
    const float* w_phi   = (const float*)d_in[3];
    const float* b_phi   = (const float*)d_in[4];
    const float* w_g     = (const float*)d_in[5];
    const float* b_g     = (const float*)d_in[6];
    const float* w_out   = (const float*)d_in[7];
    const float* b_out   = (const float*)d_in[8];
    float* y = (float*)d_out;

    const size_t SZ = (size_t)B_ * N_ * C2_;        // 2Mi elements
    u16* Q  = (u16*)d_ws;
    u16* K  = Q + SZ;
    u16* V  = K + SZ;
    u16* AO = V + SZ;
    u16* Wb = AO + SZ;                               // 4 mats x 32768 = 256 KiB
    u16* Wob = Wb + (size_t)3 * C2_ * C_;
    u16* XT = Wb + (size_t)4 * C2_ * C_;             // 8 MiB
    char* dyn = (char*)(XT + (size_t)B_ * N_ * C_);
    size_t fixedB = (size_t)(dyn - (char*)d_ws);     // ~24.5 MiB

    size_t perS = SZ * 4 + (size_t)B_ * N_ * 4;      // Op + lsum per split

    int S;
    if      (ws_size >= fixedB + 4 * perS) S = 4;
    else if (ws_size >= fixedB + 2 * perS) S = 2;
    else                                   S = 1;

    float* Op = nullptr;
    float* ls = nullptr;
    if (S > 1) {
        Op = (float*)dyn;
        ls = Op + (size_t)S * SZ;
    }

    prep_kernel<<<128 + B_ * (C_ / 64) * (N_ / 64), 256, 0, stream>>>(
        w_theta, w_phi, w_g, w_out, x, Wb, XT);
    projm_kernel<<<3 * B_ * (N_ / 64), 256, 0, stream>>>(
        XT, Wb, b_theta, b_phi, b_g, Q, K, V);
    attn_kernel<<<B_ * (N_ / 128) * S, 256, 0, stream>>>(Q, K, V, AO, Op, ls, S);
    outproj_kernel<<<B_ * (C_ / 64) * (N_ / 64), 256, 0, stream>>>(
        x, Op, ls, AO, Wob, b_out, y, S);
}